// Round 1
// baseline (90.893 us; speedup 1.0000x reference)
//
#include <hip/hip_runtime.h>

// FHE BSGS conv-as-linear-transform on MI355X.
//   out[b, s] = sum_{t=0..15} x[b, (s + 2^t) & 0xFFFF] * diag[t, s], rolled by 32768.
// Roll by S/2 on a 2^16 ring == output index s ^ 0x8000 (keeps stores coalesced).
// stride=1, reps=1 are fixed by setup_inputs() and folded into the constants below.

#define SLOTS 65536
#define MASK  65535

__global__ __launch_bounds__(256) void bsgs_kernel(
    const float* __restrict__ x,
    const float* __restrict__ diag,
    float* __restrict__ out)
{
    const int b = blockIdx.y;
    const int j = (blockIdx.x * 256 + threadIdx.x) * 4;   // column base, multiple of 4, < SLOTS
    const float* __restrict__ xb = x + (size_t)b * SLOTS;

    float4 acc = make_float4(0.f, 0.f, 0.f, 0.f);

    // Sliding window for shifts 1 and 2; vB is also the shift-4 operand.
    const float4 vA = *(const float4*)(xb + j);
    const float4 vB = *(const float4*)(xb + ((j + 4) & MASK));

    {   // t = 0, shift 1: x[j+1..j+4]
        float4 d = *(const float4*)(diag + 0 * SLOTS + j);
        acc.x += vA.y * d.x; acc.y += vA.z * d.y; acc.z += vA.w * d.z; acc.w += vB.x * d.w;
    }
    {   // t = 1, shift 2: x[j+2..j+5]
        float4 d = *(const float4*)(diag + 1 * SLOTS + j);
        acc.x += vA.z * d.x; acc.y += vA.w * d.y; acc.z += vB.x * d.z; acc.w += vB.y * d.w;
    }
    {   // t = 2, shift 4: x[j+4..j+7] == vB
        float4 d = *(const float4*)(diag + 2 * SLOTS + j);
        acc.x += vB.x * d.x; acc.y += vB.y * d.y; acc.z += vB.z * d.z; acc.w += vB.w * d.w;
    }
#pragma unroll
    for (int t = 3; t < 16; ++t) {
        const int shift = 1 << t;                      // multiple of 4 -> aligned float4
        float4 v = *(const float4*)(xb + ((j + shift) & MASK));
        float4 d = *(const float4*)(diag + t * SLOTS + j);
        acc.x += v.x * d.x; acc.y += v.y * d.y; acc.z += v.z * d.z; acc.w += v.w * d.w;
    }

    // Final roll by 32768: write to j ^ 0x8000 (still a multiple of 4; coalesced).
    *(float4*)(out + (size_t)b * SLOTS + (j ^ 32768)) = acc;
}

extern "C" void kernel_launch(void* const* d_in, const int* in_sizes, int n_in,
                              void* d_out, int out_size, void* d_ws, size_t ws_size,
                              hipStream_t stream) {
    const float* x    = (const float*)d_in[0];   // (64, 65536) fp32
    const float* diag = (const float*)d_in[1];   // (16, 65536) fp32
    float* out        = (float*)d_out;           // (64, 65536) fp32
    // d_in[2] = stride (1), d_in[3] = reps (1) -- constants for this problem.

    dim3 grid(SLOTS / (256 * 4), 64);            // 64 column-chunks x 64 batches
    bsgs_kernel<<<grid, dim3(256), 0, stream>>>(x, diag, out);
}

// Round 2
// 85.057 us; speedup vs baseline: 1.0686x; 1.0686x over previous
//
#include <hip/hip_runtime.h>

// FHE BSGS: out[b,s] = sum_{t=0..15} x[b,(s+2^t)&0xFFFF] * diag[t,s], rolled by 32768.
// Roll by S/2 on the 2^16 ring == store to column s ^ 0x8000 (coalesced).
//
// v2: block = 1024-column tile x 8 batches.
//   - diag tile in registers (16 float4/thread), reused across the 8 batches  -> diag traffic /8
//   - x footprint (7168 floats: merged segment [c,c+3072) + four 1024-col
//     segments at shifts 4096/8192/16384/32768) staged in LDS per batch        -> x traffic /2.3
// All global and LDS accesses are 16 B aligned; LDS pattern is stride-16 B
// (2-way bank aliasing = free on gfx950).

#define SLOTS 65536
#define MASK  65535
#define CTILE 1024
#define NB    8
#define XFOOT 7168   // 3072 + 4*1024 staged x floats

__global__ __launch_bounds__(256) void bsgs_kernel(
    const float* __restrict__ x,
    const float* __restrict__ diag,
    float* __restrict__ out)
{
    __shared__ float ldsx[XFOOT];
    const int tid = threadIdx.x;
    const int c   = blockIdx.x * CTILE;      // column tile base (multiple of 1024)
    const int bg  = blockIdx.y * NB;         // first batch handled by this block
    const int jj  = tid * 4;                 // this thread's column offset in tile

    // diag[t, c+jj .. c+jj+3] for t=0..15 -- 64 VGPRs, loaded once, reused NB times.
    float4 dreg[16];
#pragma unroll
    for (int t = 0; t < 16; ++t)
        dreg[t] = *(const float4*)(diag + t * SLOTS + c + jj);

    for (int b = 0; b < NB; ++b) {
        const float* __restrict__ xb = x + (size_t)(bg + b) * SLOTS;

        __syncthreads();   // previous iteration's readers done before restaging
        // Stage seg0: x[c .. c+3072)  (covers all shifts 1..2048 for jj in [0,1024))
#pragma unroll
        for (int k = 0; k < 3; ++k) {
            const int o = (tid + k * 256) * 4;
            *(float4*)(ldsx + o) = *(const float4*)(xb + ((c + o) & MASK));
        }
        // Stage segs 1..4: x[c + (4096<<s) .. +1024)
#pragma unroll
        for (int s = 0; s < 4; ++s) {
            *(float4*)(ldsx + 3072 + s * 1024 + jj) =
                *(const float4*)(xb + ((c + (4096 << s) + jj) & MASK));
        }
        __syncthreads();

        float4 acc = make_float4(0.f, 0.f, 0.f, 0.f);
        const float4 vA = *(const float4*)(ldsx + jj);       // x[c+jj .. +3]
        const float4 vB = *(const float4*)(ldsx + jj + 4);   // x[c+jj+4 .. +7]

        // t=0, shift 1
        acc.x += vA.y*dreg[0].x; acc.y += vA.z*dreg[0].y; acc.z += vA.w*dreg[0].z; acc.w += vB.x*dreg[0].w;
        // t=1, shift 2
        acc.x += vA.z*dreg[1].x; acc.y += vA.w*dreg[1].y; acc.z += vB.x*dreg[1].z; acc.w += vB.y*dreg[1].w;
        // t=2, shift 4
        acc.x += vB.x*dreg[2].x; acc.y += vB.y*dreg[2].y; acc.z += vB.z*dreg[2].z; acc.w += vB.w*dreg[2].w;
        // t=3..11, shifts 8..2048: aligned reads inside seg0 (max 1020+2048+3 = 3071)
#pragma unroll
        for (int t = 3; t <= 11; ++t) {
            const float4 v = *(const float4*)(ldsx + jj + (1 << t));
            acc.x += v.x*dreg[t].x; acc.y += v.y*dreg[t].y; acc.z += v.z*dreg[t].z; acc.w += v.w*dreg[t].w;
        }
        // t=12..15, shifts 4096/8192/16384/32768: dedicated segments
#pragma unroll
        for (int s = 0; s < 4; ++s) {
            const int t = 12 + s;
            const float4 v = *(const float4*)(ldsx + 3072 + s * 1024 + jj);
            acc.x += v.x*dreg[t].x; acc.y += v.y*dreg[t].y; acc.z += v.z*dreg[t].z; acc.w += v.w*dreg[t].w;
        }

        // roll by 32768 == XOR the top column bit; store stays coalesced
        *(float4*)(out + (size_t)(bg + b) * SLOTS + ((c + jj) ^ 32768)) = acc;
    }
}

extern "C" void kernel_launch(void* const* d_in, const int* in_sizes, int n_in,
                              void* d_out, int out_size, void* d_ws, size_t ws_size,
                              hipStream_t stream) {
    const float* x    = (const float*)d_in[0];   // (64, 65536) fp32
    const float* diag = (const float*)d_in[1];   // (16, 65536) fp32
    float* out        = (float*)d_out;           // (64, 65536) fp32
    // d_in[2] = stride (1), d_in[3] = reps (1) -- compile-time constants here.

    dim3 grid(SLOTS / CTILE, 64 / NB);           // 64 column tiles x 8 batch groups = 512 blocks
    bsgs_kernel<<<grid, dim3(256), 0, stream>>>(x, diag, out);
}